// Round 1
// baseline (7495.646 us; speedup 1.0000x reference)
//
#include <hip/hip_runtime.h>
#include <hip/hip_bf16.h>

// ---------------------------------------------------------------------------
// FlowNetC forward, fp32, MI355X. Baseline: direct convs (8 oc/thread, scalar
// weight loads), NHWC correlation, split-K flow convs, fused concat writes.
// ---------------------------------------------------------------------------

__device__ __forceinline__ int reflect_idx(int i, int n) {
  if (i < 0) i = -i;
  if (i >= n) i = 2 * n - 2 - i;
  return i;
}

// Generic direct conv. Thread = 1 output pixel x OCPT output channels.
// Weight reads are block-uniform -> scalar loads; input value reused OCPT x.
template <int K, int OCPT, bool REFLECT, bool RELU>
__global__ __launch_bounds__(256) void conv2d_k(
    const float* __restrict__ in, const float* __restrict__ w,
    const float* __restrict__ bias, float* __restrict__ out,
    int Cin, int Hi, int Wi, int Ho, int Wo,
    int stride, int pad, int Ctot, int cb) {
  const int pix = blockIdx.x * blockDim.x + threadIdx.x;
  if (pix >= Ho * Wo) return;
  const int b = blockIdx.z;
  const int oc0 = blockIdx.y * OCPT;
  const int oy = pix / Wo, ox = pix - oy * Wo;
  const int iy0 = oy * stride - pad, ix0 = ox * stride - pad;

  int iys[K], ixs[K];
  bool vy[K], vx[K];
#pragma unroll
  for (int k = 0; k < K; ++k) {
    const int iy = iy0 + k, ix = ix0 + k;
    if (REFLECT) {
      iys[k] = reflect_idx(iy, Hi); vy[k] = true;
      ixs[k] = reflect_idx(ix, Wi); vx[k] = true;
    } else {
      vy[k] = (iy >= 0 && iy < Hi); iys[k] = vy[k] ? iy : 0;
      vx[k] = (ix >= 0 && ix < Wi); ixs[k] = vx[k] ? ix : 0;
    }
  }

  float acc[OCPT];
#pragma unroll
  for (int o = 0; o < OCPT; ++o) acc[o] = bias ? bias[oc0 + o] : 0.0f;

  const size_t hw = (size_t)Hi * Wi;
  const float* inb = in + (size_t)b * Cin * hw;
  const int wstride = Cin * K * K;

  for (int ci = 0; ci < Cin; ++ci) {
    const float* inc = inb + (size_t)ci * hw;
    const float* wc = w + (size_t)oc0 * wstride + (size_t)ci * (K * K);
#pragma unroll
    for (int kh = 0; kh < K; ++kh) {
      const float* inr = inc + iys[kh] * Wi;
#pragma unroll
      for (int kw = 0; kw < K; ++kw) {
        float v;
        if (REFLECT) {
          v = inr[ixs[kw]];
        } else {
          v = (vy[kh] && vx[kw]) ? inr[ixs[kw]] : 0.0f;
        }
#pragma unroll
        for (int o = 0; o < OCPT; ++o)
          acc[o] = fmaf(wc[(size_t)o * wstride + kh * K + kw], v, acc[o]);
      }
    }
  }

  float* op = out + (((size_t)b * Ctot + cb + oc0) * Ho + oy) * Wo + ox;
#pragma unroll
  for (int o = 0; o < OCPT; ++o) {
    float r = acc[o];
    if (RELU) r = fmaxf(r, 0.0f);
    op[(size_t)o * Ho * Wo] = r;
  }
}

// NCHW -> NHWC transpose (tiled, conflict-free LDS).
__global__ __launch_bounds__(256) void nchw_to_nhwc(
    const float* __restrict__ in, float* __restrict__ out, int C, int HW) {
  __shared__ float t[32][65];
  const int b = blockIdx.z;
  const int p0 = blockIdx.x * 64, c0 = blockIdx.y * 32;
  const int tx = threadIdx.x & 63, ty = threadIdx.x >> 6;  // ty 0..3
  for (int i = ty; i < 32; i += 4) {
    const int p = p0 + tx;
    t[i][tx] = (p < HW) ? in[((size_t)b * C + c0 + i) * HW + p] : 0.0f;
  }
  __syncthreads();
  const int cx = threadIdx.x & 31, py = threadIdx.x >> 5;  // py 0..7
  for (int i = py; i < 64; i += 8) {
    const int p = p0 + i;
    if (p < HW) out[((size_t)b * HW + p) * C + c0 + cx] = t[cx][i];
  }
}

// corr[b, off, i, j] = sum_c corrA[b,c,i+di-10,j+dj-10] * corrB[b,c,i,j]
// Inputs pre-transposed to NHWC so the 256-ch dot is contiguous float4.
// One block per (b, pixel); corrB row staged in LDS; threads cover offsets.
__global__ __launch_bounds__(256) void corr_kernel(
    const float* __restrict__ tA, const float* __restrict__ tB,
    float* __restrict__ out, int Ctot) {
  const int C = 256, H = 48, W = 48, HW = 2304;
  const int b = blockIdx.y;
  const int p = blockIdx.x;
  const int i = p / W, j = p - i * W;
  __shared__ float xb[256];
  xb[threadIdx.x] = tB[((size_t)b * HW + p) * C + threadIdx.x];
  __syncthreads();
  const float4* b4 = (const float4*)xb;
  for (int off = threadIdx.x; off < 441; off += 256) {
    const int di = off / 21 - 10, dj = off - (off / 21) * 21 - 10;
    const int ii = i + di, jj = j + dj;
    float acc = 0.0f;
    if (ii >= 0 && ii < H && jj >= 0 && jj < W) {
      const float4* a4 = (const float4*)(tA + ((size_t)b * HW + ii * W + jj) * C);
#pragma unroll 8
      for (int c4 = 0; c4 < 64; ++c4) {
        const float4 av = a4[c4], bv = b4[c4];
        acc += av.x * bv.x + av.y * bv.y + av.z * bv.z + av.w * bv.w;
      }
    }
    out[(((size_t)b * Ctot + off) * H + i) * W + j] = acc;
  }
}

// ConvTranspose2d(ks=1,s=2,outpad=1)+ReLU: 1x1 proj at even positions, zeros
// elsewhere (written explicitly -- ws is poisoned). w layout: [Cin][Cout].
__global__ __launch_bounds__(256) void upconv_kernel(
    const float* __restrict__ x, const float* __restrict__ w,
    float* __restrict__ y, int Cin, int Cout, int H, int W, int Ctot, int cb) {
  const int b = blockIdx.y;
  const int hw = H * W;
  const int total = Cout * hw;
  const int idx = blockIdx.x * blockDim.x + threadIdx.x;
  if (idx >= total) return;
  const int oc = idx / hw;
  const int p = idx - oc * hw;
  const int h = p / W, wx = p - h * W;
  const float* xb = x + (size_t)b * Cin * hw + p;
  float acc = 0.0f;
  for (int ci = 0; ci < Cin; ++ci)
    acc = fmaf(xb[(size_t)ci * hw], w[(size_t)ci * Cout + oc], acc);
  const float r = fmaxf(acc, 0.0f);
  const int Wo = 2 * W;
  float* yp = y + (((size_t)b * Ctot + cb + oc) * (2 * H) + 2 * h) * Wo + 2 * wx;
  yp[0] = r; yp[1] = 0.0f; yp[Wo] = 0.0f; yp[Wo + 1] = 0.0f;
}

// Copy src [B][Cs][HW] into channel slice [cb, cb+Cs) of dst [B][Ctot][HW].
__global__ __launch_bounds__(256) void copy_ch(
    const float* __restrict__ src, float* __restrict__ dst,
    int Cs, int HW, int Ctot, int cb) {
  const int b = blockIdx.y;
  const int total = Cs * HW;
  for (int idx = blockIdx.x * blockDim.x + threadIdx.x; idx < total;
       idx += gridDim.x * blockDim.x) {
    const int c = idx / HW, p = idx - (idx / HW) * HW;
    dst[((size_t)b * Ctot + cb + c) * HW + p] = src[((size_t)b * Cs + c) * HW + p];
  }
}

// Bilinear upsample, align_corners=True, into a channel slice of dst.
__global__ __launch_bounds__(256) void upsample_bilinear(
    const float* __restrict__ in, float* __restrict__ out,
    int C, int Hi, int Wi, int Ho, int Wo, int Ctot, int cb) {
  const int b = blockIdx.y;
  const int total = C * Ho * Wo;
  const float sh = (float)(Hi - 1) / (float)(Ho - 1);
  const float sw = (float)(Wi - 1) / (float)(Wo - 1);
  for (int idx = blockIdx.x * blockDim.x + threadIdx.x; idx < total;
       idx += gridDim.x * blockDim.x) {
    const int c = idx / (Ho * Wo);
    const int p = idx - c * (Ho * Wo);
    const int oy = p / Wo, ox = p - oy * Wo;
    const float fy = oy * sh, fx = ox * sw;
    int y0 = (int)fy; if (y0 > Hi - 2) y0 = Hi - 2;
    int x0 = (int)fx; if (x0 > Wi - 2) x0 = Wi - 2;
    const float wy = fy - y0, wx = fx - x0;
    const float* ib = in + ((size_t)b * C + c) * Hi * Wi;
    const float v00 = ib[y0 * Wi + x0], v01 = ib[y0 * Wi + x0 + 1];
    const float v10 = ib[(y0 + 1) * Wi + x0], v11 = ib[(y0 + 1) * Wi + x0 + 1];
    const float r0 = v00 * (1.0f - wy) + v10 * wy;
    const float r1 = v01 * (1.0f - wy) + v11 * wy;
    out[((size_t)b * Ctot + cb + c) * Ho * Wo + p] = r0 * (1.0f - wx) + r1 * wx;
  }
}

// Flow convs: K=5, zero pad 2, stride 1, Cout=2, no bias, no relu.
// Split-K over input channels with atomicAdd (outputs pre-zeroed).
__global__ __launch_bounds__(256) void conv5_splitk(
    const float* __restrict__ in, const float* __restrict__ w,
    float* __restrict__ out, int Cin, int Hi, int Wi, int cChunk) {
  const int b = blockIdx.z;
  const int c0 = blockIdx.y * cChunk;
  const int c1 = min(c0 + cChunk, Cin);
  const int pix = blockIdx.x * blockDim.x + threadIdx.x;
  if (pix >= Hi * Wi) return;
  const int oy = pix / Wi, ox = pix - oy * Wi;
  float acc0 = 0.0f, acc1 = 0.0f;
  const size_t hw = (size_t)Hi * Wi;
  for (int ci = c0; ci < c1; ++ci) {
    const float* inc = in + ((size_t)b * Cin + ci) * hw;
    const float* wc0 = w + (size_t)ci * 25;
    const float* wc1 = w + ((size_t)Cin + ci) * 25;
#pragma unroll
    for (int kh = 0; kh < 5; ++kh) {
      const int iy = oy - 2 + kh;
      if (iy < 0 || iy >= Hi) continue;
#pragma unroll
      for (int kw = 0; kw < 5; ++kw) {
        const int ix = ox - 2 + kw;
        if (ix < 0 || ix >= Wi) continue;
        const float v = inc[iy * Wi + ix];
        acc0 = fmaf(wc0[kh * 5 + kw], v, acc0);
        acc1 = fmaf(wc1[kh * 5 + kw], v, acc1);
      }
    }
  }
  const size_t o = (size_t)b * 2 * hw + pix;
  atomicAdd(&out[o], acc0);
  atomicAdd(&out[o + hw], acc1);
}

static inline int cdiv(int a, int b) { return (a + b - 1) / b; }

extern "C" void kernel_launch(void* const* d_in, const int* in_sizes, int n_in,
                              void* d_out, int out_size, void* d_ws, size_t ws_size,
                              hipStream_t stream) {
  (void)in_sizes; (void)n_in; (void)out_size; (void)ws_size;
  const float* im1     = (const float*)d_in[0];
  const float* im2     = (const float*)d_in[1];
  const float* wA1     = (const float*)d_in[2];
  const float* wA2     = (const float*)d_in[3];
  const float* wA3     = (const float*)d_in[4];
  const float* wB1     = (const float*)d_in[5];
  const float* wB2     = (const float*)d_in[6];
  const float* wB3     = (const float*)d_in[7];
  const float* w_redir = (const float*)d_in[8];
  const float* b_redir = (const float*)d_in[9];
  const float* w3_1    = (const float*)d_in[10];
  const float* w4      = (const float*)d_in[11];
  const float* w4_1    = (const float*)d_in[12];
  const float* w5      = (const float*)d_in[13];
  const float* w5_1    = (const float*)d_in[14];
  const float* w6      = (const float*)d_in[15];
  const float* wd5     = (const float*)d_in[16];
  const float* wd4     = (const float*)d_in[17];
  const float* wd3     = (const float*)d_in[18];
  const float* wd2     = (const float*)d_in[19];
  const float* wf5     = (const float*)d_in[20];
  const float* wf4     = (const float*)d_in[21];
  const float* wf3     = (const float*)d_in[22];
  const float* wf3_    = wf3;
  const float* wpred   = (const float*)d_in[23];

  float* ws = (float*)d_ws;
  size_t off = 0;
  auto alloc = [&](size_t n) { float* p = ws + off; off += n; return p; };
  // Arena (~186 MB of fp32).
  float* T1    = alloc(9437184);  // [4,64,192,192]  conv1 out (both branches)
  float* A     = alloc(4718592);  // [4,128,96,96]   persistent (y2 concat)
  float* CORRA = alloc(2359296);  // [4,256,48,48]
  float* B2    = alloc(4718592);  // [4,128,96,96]
  float* CORRB = alloc(2359296);  // [4,256,48,48]
  float* TA    = alloc(2359296);  // NHWC corrA
  float* TB    = alloc(2359296);  // NHWC corrB
  float* X     = alloc(4359168);  // [4,473,48,48]   corr(0:441)+redir(441:473)
  float* X2    = alloc(2359296);  // [4,256,48,48]   persistent
  float* T3    = alloc(1179648);  // [4,512,24,24]
  float* X3    = alloc(1179648);  // [4,512,24,24]   persistent
  float* T4    = alloc(294912);   // [4,512,12,12]
  float* X4    = alloc(294912);   // [4,512,12,12]   persistent
  float* X5    = alloc(147456);   // [4,1024,6,6]
  float* Y5    = alloc(589824);   // [4,1024,12,12]
  float* F5    = alloc(1152);     // [4,2,12,12]
  float* Y4    = alloc(1774080);  // [4,770,24,24]
  float* F4    = alloc(4608);     // [4,2,24,24]
  float* Y3    = alloc(3557376);  // [4,386,48,48]
  float* F3    = alloc(18432);    // [4,2,48,48]
  float* Y2    = alloc(7151616);  // [4,194,96,96]
  float* PRED  = alloc(73728);    // [4,2,96,96]

  const int B = 4;

  // ---- feature extractor A ----
  { dim3 g(cdiv(192*192,256), 64/8, B);
    conv2d_k<7,8,true,true><<<g,256,0,stream>>>(im1, wA1, nullptr, T1, 3, 384,384, 192,192, 2,3, 64,0); }
  { dim3 g(cdiv(96*96,256), 128/8, B);
    conv2d_k<5,8,true,true><<<g,256,0,stream>>>(T1, wA2, nullptr, A, 64, 192,192, 96,96, 2,2, 128,0); }
  { dim3 g(cdiv(48*48,256), 256/8, B);
    conv2d_k<5,8,true,true><<<g,256,0,stream>>>(A, wA3, nullptr, CORRA, 128, 96,96, 48,48, 2,2, 256,0); }
  // ---- feature extractor B ----
  { dim3 g(cdiv(192*192,256), 64/8, B);
    conv2d_k<7,8,true,true><<<g,256,0,stream>>>(im2, wB1, nullptr, T1, 3, 384,384, 192,192, 2,3, 64,0); }
  { dim3 g(cdiv(96*96,256), 128/8, B);
    conv2d_k<5,8,true,true><<<g,256,0,stream>>>(T1, wB2, nullptr, B2, 64, 192,192, 96,96, 2,2, 128,0); }
  { dim3 g(cdiv(48*48,256), 256/8, B);
    conv2d_k<5,8,true,true><<<g,256,0,stream>>>(B2, wB3, nullptr, CORRB, 128, 96,96, 48,48, 2,2, 256,0); }

  // ---- correlation (NHWC) + redir into X ----
  { dim3 g(2304/64, 256/32, B); nchw_to_nhwc<<<g,256,0,stream>>>(CORRA, TA, 256, 2304); }
  { dim3 g(2304/64, 256/32, B); nchw_to_nhwc<<<g,256,0,stream>>>(CORRB, TB, 256, 2304); }
  { dim3 g(2304, B); corr_kernel<<<g,256,0,stream>>>(TA, TB, X, 473); }
  { dim3 g(cdiv(48*48,256), 32/8, B);
    conv2d_k<1,8,true,true><<<g,256,0,stream>>>(CORRA, w_redir, b_redir, X, 256, 48,48, 48,48, 1,0, 473,441); }

  // ---- encoder ----
  { dim3 g(cdiv(48*48,256), 256/8, B);
    conv2d_k<3,8,true,true><<<g,256,0,stream>>>(X, w3_1, nullptr, X2, 473, 48,48, 48,48, 1,1, 256,0); }
  { dim3 g(cdiv(24*24,64), 512/8, B);
    conv2d_k<3,8,true,true><<<g,64,0,stream>>>(X2, w4, nullptr, T3, 256, 48,48, 24,24, 2,1, 512,0); }
  { dim3 g(cdiv(24*24,64), 512/8, B);
    conv2d_k<3,8,true,true><<<g,64,0,stream>>>(T3, w4_1, nullptr, X3, 512, 24,24, 24,24, 1,1, 512,0); }
  { dim3 g(cdiv(12*12,64), 512/4, B);
    conv2d_k<3,4,true,true><<<g,64,0,stream>>>(X3, w5, nullptr, T4, 512, 24,24, 12,12, 2,1, 512,0); }
  { dim3 g(cdiv(12*12,64), 512/4, B);
    conv2d_k<3,4,true,true><<<g,64,0,stream>>>(T4, w5_1, nullptr, X4, 512, 12,12, 12,12, 1,1, 512,0); }
  { dim3 g(cdiv(6*6,64), 1024/4, B);
    conv2d_k<3,4,true,true><<<g,64,0,stream>>>(X4, w6, nullptr, X5, 512, 12,12, 6,6, 2,1, 1024,0); }

  // ---- decoder level 5 -> flow5 ----
  { dim3 g(cdiv(512*36,256), B);  upconv_kernel<<<g,256,0,stream>>>(X5, wd5, Y5, 1024, 512, 6,6, 1024, 0); }
  { dim3 g(cdiv(512*144,256), B); copy_ch<<<g,256,0,stream>>>(X4, Y5, 512, 144, 1024, 512); }
  hipMemsetAsync(F5, 0, 1152*sizeof(float), stream);
  { dim3 g(cdiv(144,64), cdiv(1024,64), B); conv5_splitk<<<g,64,0,stream>>>(Y5, wf5, F5, 1024, 12,12, 64); }

  // ---- decoder level 4 -> flow4 ----
  { dim3 g(cdiv(256*144,256), B); upconv_kernel<<<g,256,0,stream>>>(Y5, wd4, Y4, 1024, 256, 12,12, 770, 0); }
  { dim3 g(cdiv(512*576,256), B); copy_ch<<<g,256,0,stream>>>(X3, Y4, 512, 576, 770, 256); }
  { dim3 g(cdiv(2*576,256), B);   upsample_bilinear<<<g,256,0,stream>>>(F5, Y4, 2, 12,12, 24,24, 770, 768); }
  hipMemsetAsync(F4, 0, 4608*sizeof(float), stream);
  { dim3 g(cdiv(576,64), cdiv(770,64), B); conv5_splitk<<<g,64,0,stream>>>(Y4, wf4, F4, 770, 24,24, 64); }

  // ---- decoder level 3 -> flow3 ----
  { dim3 g(cdiv(128*576,256), B);  upconv_kernel<<<g,256,0,stream>>>(Y4, wd3, Y3, 770, 128, 24,24, 386, 0); }
  { dim3 g(cdiv(256*2304,256), B); copy_ch<<<g,256,0,stream>>>(X2, Y3, 256, 2304, 386, 128); }
  { dim3 g(cdiv(2*2304,256), B);   upsample_bilinear<<<g,256,0,stream>>>(F4, Y3, 2, 24,24, 48,48, 386, 384); }
  hipMemsetAsync(F3, 0, 18432*sizeof(float), stream);
  { dim3 g(cdiv(2304,256), cdiv(386,64), B); conv5_splitk<<<g,256,0,stream>>>(Y3, wf3_, F3, 386, 48,48, 64); }

  // ---- decoder level 2 -> pred ----
  { dim3 g(cdiv(64*2304,256), B);  upconv_kernel<<<g,256,0,stream>>>(Y3, wd2, Y2, 386, 64, 48,48, 194, 0); }
  { dim3 g(cdiv(128*9216,256), B); copy_ch<<<g,256,0,stream>>>(A, Y2, 128, 9216, 194, 64); }
  { dim3 g(cdiv(2*9216,256), B);   upsample_bilinear<<<g,256,0,stream>>>(F3, Y2, 2, 48,48, 96,96, 194, 192); }
  hipMemsetAsync(PRED, 0, 73728*sizeof(float), stream);
  { dim3 g(cdiv(9216,256), cdiv(194,64), B); conv5_splitk<<<g,256,0,stream>>>(Y2, wpred, PRED, 194, 96,96, 64); }

  // ---- final x4 bilinear upsample to output ----
  { dim3 g(cdiv(2*384*384,256), B);
    upsample_bilinear<<<g,256,0,stream>>>(PRED, (float*)d_out, 2, 96,96, 384,384, 2, 0); }
}

// Round 9
// 4960.301 us; speedup vs baseline: 1.5111x; 1.5111x over previous
//
#include <hip/hip_runtime.h>
#include <hip/hip_bf16.h>

// ---------------------------------------------------------------------------
// FlowNetC forward, MI355X. Round 9 (= Round 4-8 resubmit, never yet run):
// implicit-GEMM MFMA convs (bf16 hi/lo split, fp32 accumulate), NHWC bf16
// activations. Memory restructured to 184 MB (< ~196 MB proven ws_size):
// sequential branches share T1/C2; late-packed weights + decoder buffers
// overlay dead regions.
// ---------------------------------------------------------------------------

typedef unsigned short u16;
typedef __attribute__((ext_vector_type(8))) short short8;
typedef __attribute__((ext_vector_type(4))) float f32x4;

__device__ __forceinline__ int reflect_idx(int i, int n) {
  if (i < 0) i = -i;
  if (i >= n) i = 2 * n - 2 - i;
  return i;
}

__device__ __forceinline__ u16 f2bf(float f) {       // RTN-even fp32 -> bf16
  unsigned u = __float_as_uint(f);
  u += 0x7FFFu + ((u >> 16) & 1u);
  return (u16)(u >> 16);
}
__device__ __forceinline__ float bf2f(u16 h) {
  return __uint_as_float((unsigned)h << 16);
}

typedef __attribute__((address_space(1))) const unsigned int gu32;
typedef __attribute__((address_space(3))) unsigned int lu32;
__device__ __forceinline__ void gload16(const void* g, void* l) {
  // async global->LDS, 16B per lane; LDS dest = wave-uniform base + lane*16
  __builtin_amdgcn_global_load_lds((gu32*)g, (lu32*)l, 16, 0, 0);
}

// ---------------------------------------------------------------------------
// Weight pack: w[O][Ci][KH][KW] fp32 -> hi/lo bf16 [O][K], K=(kh*KW+kw)*Cip+ci,
// zero-filled for ci >= Ci (matches NHWC B-operand k ordering).
// ---------------------------------------------------------------------------
__global__ __launch_bounds__(256) void pack_w(
    const float* __restrict__ w, u16* __restrict__ hi, u16* __restrict__ lo,
    int O, int Ci, int Cip, int KH, int KW) {
  const long K = (long)Cip * KH * KW;
  const long total = (long)O * K;
  long idx = (long)blockIdx.x * 256 + threadIdx.x;
  if (idx >= total) return;
  const int o = (int)(idx / K);
  const long k = idx - (long)o * K;
  const int q = (int)(k / Cip), ci = (int)(k - (long)q * Cip);
  const int kh = q / KW, kw = q - kh * KW;
  const float v = (ci < Ci) ? w[(((size_t)o * Ci + ci) * KH + kh) * KW + kw] : 0.f;
  const u16 h = f2bf(v);
  hi[idx] = h;
  lo[idx] = f2bf(v - bf2f(h));
}

// ---------------------------------------------------------------------------
// Direct conv (fp32 math) writing bf16 hi/lo NHWC into a padded buffer
// interior. Used for conv1 (Ci=3) and redir (1x1). Reflect pad, ReLU.
// ---------------------------------------------------------------------------
template <int K, int OCPT>
__global__ __launch_bounds__(256) void conv_direct_nhwc(
    const float* __restrict__ in, const float* __restrict__ w,
    const float* __restrict__ bias, u16* __restrict__ outhi,
    u16* __restrict__ outlo, int Cin, int Hi, int Wi, int Ho, int Wo,
    int stride, int pad, int Cip, int Hp, int Wp, int pad2, int cb) {
  const int pix = blockIdx.x * blockDim.x + threadIdx.x;
  if (pix >= Ho * Wo) return;
  const int b = blockIdx.z;
  const int oc0 = blockIdx.y * OCPT;
  const int oy = pix / Wo, ox = pix - oy * Wo;
  const int iy0 = oy * stride - pad, ix0 = ox * stride - pad;
  int iys[K], ixs[K];
#pragma unroll
  for (int k = 0; k < K; ++k) {
    iys[k] = reflect_idx(iy0 + k, Hi);
    ixs[k] = reflect_idx(ix0 + k, Wi);
  }
  float acc[OCPT];
#pragma unroll
  for (int o = 0; o < OCPT; ++o) acc[o] = bias ? bias[oc0 + o] : 0.0f;
  const size_t hw = (size_t)Hi * Wi;
  const float* inb = in + (size_t)b * Cin * hw;
  const int wstride = Cin * K * K;
  for (int ci = 0; ci < Cin; ++ci) {
    const float* inc = inb + (size_t)ci * hw;
    const float* wc = w + (size_t)oc0 * wstride + (size_t)ci * (K * K);
#pragma unroll
    for (int kh = 0; kh < K; ++kh) {
      const float* inr = inc + iys[kh] * Wi;
#pragma unroll
      for (int kw = 0; kw < K; ++kw) {
        const float v = inr[ixs[kw]];
#pragma unroll
        for (int o = 0; o < OCPT; ++o)
          acc[o] = fmaf(wc[(size_t)o * wstride + kh * K + kw], v, acc[o]);
      }
    }
  }
  const size_t o2 = ((size_t)(b * Hp + oy + pad2) * Wp + ox + pad2) * Cip + cb + oc0;
#pragma unroll
  for (int o = 0; o < OCPT; ++o) {
    const float r = fmaxf(acc[o], 0.0f);
    const u16 h = f2bf(r);
    outhi[o2 + o] = h;
    outlo[o2 + o] = f2bf(r - bf2f(h));
  }
}

// ---------------------------------------------------------------------------
// Reflect-pad halo fill for NHWC bf16 buffers (interior must be written).
// ---------------------------------------------------------------------------
__global__ __launch_bounds__(256) void halo_fill(
    u16* __restrict__ hi, u16* __restrict__ lo,
    int H, int W, int pad, int C, int Hp, int Wp) {
  const int b = blockIdx.y;
  const long idx = (long)blockIdx.x * 256 + threadIdx.x;
  if (idx >= (long)Hp * Wp * C) return;
  const int c = (int)(idx % C);
  const int cell = (int)(idx / C);
  const int x = cell % Wp, y = cell / Wp;
  if (y >= pad && y < H + pad && x >= pad && x < W + pad) return;
  const int sy = pad + reflect_idx(y - pad, H);
  const int sx = pad + reflect_idx(x - pad, W);
  const size_t dst = ((size_t)(b * Hp + y) * Wp + x) * C + c;
  const size_t src = ((size_t)(b * Hp + sy) * Wp + sx) * C + c;
  hi[dst] = hi[src];
  lo[dst] = lo[src];
}

// ---------------------------------------------------------------------------
// Correlation: corr[b,off,i,j] = sum_c tA[b,c,i+di,j+dj]*tB[b,c,i,j]
// tA/tB fp32 NHWC [B][2304][256]. Writes X NHWC bf16 hi/lo (Cip=480, pad2=1).
// ---------------------------------------------------------------------------
__global__ __launch_bounds__(256) void corr_kernel(
    const float* __restrict__ tA, const float* __restrict__ tB,
    u16* __restrict__ Xh, u16* __restrict__ Xl) {
  const int C = 256, H = 48, W = 48, HW = 2304;
  const int b = blockIdx.y;
  const int p = blockIdx.x;
  const int i = p / W, j = p - i * W;
  __shared__ float xb[256];
  xb[threadIdx.x] = tB[((size_t)b * HW + p) * C + threadIdx.x];
  __syncthreads();
  const float4* b4 = (const float4*)xb;
  for (int off = threadIdx.x; off < 441; off += 256) {
    const int di = off / 21 - 10, dj = off - (off / 21) * 21 - 10;
    const int ii = i + di, jj = j + dj;
    float acc = 0.0f;
    if (ii >= 0 && ii < H && jj >= 0 && jj < W) {
      const float4* a4 = (const float4*)(tA + ((size_t)b * HW + ii * W + jj) * C);
#pragma unroll 8
      for (int c4 = 0; c4 < 64; ++c4) {
        const float4 av = a4[c4], bv = b4[c4];
        acc += av.x * bv.x + av.y * bv.y + av.z * bv.z + av.w * bv.w;
      }
    }
    const size_t o = ((size_t)(b * 50 + i + 1) * 50 + (j + 1)) * 480 + off;
    const u16 h = f2bf(acc);
    Xh[o] = h;
    Xl[o] = f2bf(acc - bf2f(h));
  }
}

// ---------------------------------------------------------------------------
// Implicit-GEMM MFMA conv. C[M x N] = W[M x K] * im2col(X)[K x N], ReLU.
// M = Cout, N = B*Ho*Wo, K = KH*KW*Cip, bf16 hi/lo split (3 MFMAs / k-step).
// Block 256 thr = 4 waves (2x2), tile 128x128, BK=32, single-buffer 2-barrier.
// LDS tile layout [kgroup(4)][row(128)][8 elems].
// Epilogue: fp32 NCHW (opt) + fp32 NHWC (opt) + bf16 hi/lo padded-NHWC (opt).
// ---------------------------------------------------------------------------
struct GemmP {
  const u16 *Ah, *Al, *Bh, *Bl;
  float *C;                     // fp32 NCHW out (opt)
  float *F;                     // fp32 NHWC out, unpadded (opt)
  u16 *Nh, *Nl;                 // bf16 NHWC padded out (opt)
  int M, N, K, Cip, Ho, Wo, HoWo, stride, KW, Hp, Wp;
  int Hp2, Wp2, pad2;
};

__global__ __launch_bounds__(256) void gemm_conv(GemmP g) {
  const int tid = threadIdx.x;
  const int lane = tid & 63, wid = tid >> 6;
  const int wr = wid >> 1, wc = wid & 1;
  const int n0 = blockIdx.x * 128, m0 = blockIdx.y * 128;

  __shared__ __align__(16) u16 sAh[4096], sAl[4096], sBh[4096], sBl[4096];

  // per-thread staging slots: s = i*256 + tid; kgroup = s>>7, row = s&127
  size_t aoff[2], boff[2];
#pragma unroll
  for (int i = 0; i < 2; ++i) {
    const int s = i * 256 + tid, gs = s >> 7, r = s & 127;
    aoff[i] = (size_t)(m0 + r) * g.K + gs * 8;
    int n = n0 + r;
    if (n >= g.N) n = g.N - 1;
    const int b = n / g.HoWo, p = n - b * g.HoWo;
    const int oy = p / g.Wo, ox = p - oy * g.Wo;
    boff[i] = ((size_t)(b * g.Hp + oy * g.stride) * g.Wp + ox * g.stride) * (size_t)g.Cip + gs * 8;
  }

  f32x4 acc[4][4];
#pragma unroll
  for (int m = 0; m < 4; ++m)
#pragma unroll
    for (int n = 0; n < 4; ++n) acc[m][n] = f32x4{0.f, 0.f, 0.f, 0.f};

  int ci0 = 0, kwc = 0, khw_off = 0;                 // khw_off = (kh*Wp+kw)*Cip
  const int rowAdd = (g.Wp - (g.KW - 1)) * g.Cip;
  for (int k0 = 0; k0 < g.K; k0 += 32) {
    const size_t ka = (size_t)k0;
    const size_t kb = (size_t)khw_off + ci0;
    __syncthreads();
#pragma unroll
    for (int i = 0; i < 2; ++i) {
      const int lo_ = (i * 256 + wid * 64) * 8;      // u16 offset, wave-uniform
      gload16(g.Ah + aoff[i] + ka, &sAh[lo_]);
      gload16(g.Al + aoff[i] + ka, &sAl[lo_]);
      gload16(g.Bh + boff[i] + kb, &sBh[lo_]);
      gload16(g.Bl + boff[i] + kb, &sBl[lo_]);
    }
    __syncthreads();   // compiler drains vmcnt before s_barrier

    const int fr = lane & 15, fs = (lane >> 4) * 128;
    short8 ah[4], al[4], bh[4], bl[4];
#pragma unroll
    for (int m = 0; m < 4; ++m) {
      const int ra = (fs + wr * 64 + m * 16 + fr) * 8;
      ah[m] = *(const short8*)&sAh[ra];
      al[m] = *(const short8*)&sAl[ra];
      const int rb = (fs + wc * 64 + m * 16 + fr) * 8;
      bh[m] = *(const short8*)&sBh[rb];
      bl[m] = *(const short8*)&sBl[rb];
    }
#pragma unroll
    for (int m = 0; m < 4; ++m)
#pragma unroll
      for (int n = 0; n < 4; ++n) {
        acc[m][n] = __builtin_amdgcn_mfma_f32_16x16x32_bf16(ah[m], bh[n], acc[m][n], 0, 0, 0);
        acc[m][n] = __builtin_amdgcn_mfma_f32_16x16x32_bf16(ah[m], bl[n], acc[m][n], 0, 0, 0);
        acc[m][n] = __builtin_amdgcn_mfma_f32_16x16x32_bf16(al[m], bh[n], acc[m][n], 0, 0, 0);
      }
    ci0 += 32;
    if (ci0 >= g.Cip) {
      ci0 = 0;
      ++kwc;
      if (kwc == g.KW) { kwc = 0; khw_off += rowAdd; }
      else khw_off += g.Cip;
    }
  }

  // epilogue: C/D layout col=lane&15 (pixel), row=(lane>>4)*4+j (oc)
  const int colL = lane & 15, rg = (lane >> 4) * 4;
#pragma unroll
  for (int n = 0; n < 4; ++n) {
    const int np = n0 + wc * 64 + n * 16 + colL;
    if (np >= g.N) continue;
    const int b = np / g.HoWo, p = np - b * g.HoWo;
    const int oy = p / g.Wo, ox = p - oy * g.Wo;
#pragma unroll
    for (int m = 0; m < 4; ++m) {
      const int oc0 = m0 + wr * 64 + m * 16 + rg;
      float vv[4];
#pragma unroll
      for (int j = 0; j < 4; ++j) vv[j] = fmaxf(acc[m][n][j], 0.0f);
      if (g.C) {
        const size_t base = ((size_t)b * g.M + oc0) * g.HoWo + p;
#pragma unroll
        for (int j = 0; j < 4; ++j) g.C[base + (size_t)j * g.HoWo] = vv[j];
      }
      if (g.F) {
        float4 f4 = {vv[0], vv[1], vv[2], vv[3]};
        *(float4*)&g.F[((size_t)b * g.HoWo + p) * g.M + oc0] = f4;
      }
      if (g.Nh) {
        const size_t a2 =
            ((size_t)(b * g.Hp2 + oy + g.pad2) * g.Wp2 + ox + g.pad2) * (size_t)g.M + oc0;
        ushort4 h4, l4;
        h4.x = f2bf(vv[0]); h4.y = f2bf(vv[1]); h4.z = f2bf(vv[2]); h4.w = f2bf(vv[3]);
        l4.x = f2bf(vv[0] - bf2f(h4.x)); l4.y = f2bf(vv[1] - bf2f(h4.y));
        l4.z = f2bf(vv[2] - bf2f(h4.z)); l4.w = f2bf(vv[3] - bf2f(h4.w));
        *(ushort4*)&g.Nh[a2] = h4;
        *(ushort4*)&g.Nl[a2] = l4;
      }
    }
  }
}

// ---------------------------------------------------------------------------
// Decoder kernels (fp32, from the verified baseline)
// ---------------------------------------------------------------------------
__global__ __launch_bounds__(256) void upconv_kernel(
    const float* __restrict__ x, const float* __restrict__ w,
    float* __restrict__ y, int Cin, int Cout, int H, int W, int Ctot, int cb) {
  const int b = blockIdx.y;
  const int hw = H * W;
  const int total = Cout * hw;
  const int idx = blockIdx.x * blockDim.x + threadIdx.x;
  if (idx >= total) return;
  const int oc = idx / hw;
  const int p = idx - oc * hw;
  const int h = p / W, wx = p - h * W;
  const float* xb = x + (size_t)b * Cin * hw + p;
  float acc = 0.0f;
  for (int ci = 0; ci < Cin; ++ci)
    acc = fmaf(xb[(size_t)ci * hw], w[(size_t)ci * Cout + oc], acc);
  const float r = fmaxf(acc, 0.0f);
  const int Wo = 2 * W;
  float* yp = y + (((size_t)b * Ctot + cb + oc) * (2 * H) + 2 * h) * Wo + 2 * wx;
  yp[0] = r; yp[1] = 0.0f; yp[Wo] = 0.0f; yp[Wo + 1] = 0.0f;
}

__global__ __launch_bounds__(256) void copy_ch(
    const float* __restrict__ src, float* __restrict__ dst,
    int Cs, int HW, int Ctot, int cb) {
  const int b = blockIdx.y;
  const int total = Cs * HW;
  for (int idx = blockIdx.x * blockDim.x + threadIdx.x; idx < total;
       idx += gridDim.x * blockDim.x) {
    const int c = idx / HW, p = idx - (idx / HW) * HW;
    dst[((size_t)b * Ctot + cb + c) * HW + p] = src[((size_t)b * Cs + c) * HW + p];
  }
}

__global__ __launch_bounds__(256) void upsample_bilinear(
    const float* __restrict__ in, float* __restrict__ out,
    int C, int Hi, int Wi, int Ho, int Wo, int Ctot, int cb) {
  const int b = blockIdx.y;
  const int total = C * Ho * Wo;
  const float sh = (float)(Hi - 1) / (float)(Ho - 1);
  const float sw = (float)(Wi - 1) / (float)(Wo - 1);
  for (int idx = blockIdx.x * blockDim.x + threadIdx.x; idx < total;
       idx += gridDim.x * blockDim.x) {
    const int c = idx / (Ho * Wo);
    const int p = idx - c * (Ho * Wo);
    const int oy = p / Wo, ox = p - oy * Wo;
    const float fy = oy * sh, fx = ox * sw;
    int y0 = (int)fy; if (y0 > Hi - 2) y0 = Hi - 2;
    int x0 = (int)fx; if (x0 > Wi - 2) x0 = Wi - 2;
    const float wy = fy - y0, wx = fx - x0;
    const float* ib = in + ((size_t)b * C + c) * Hi * Wi;
    const float v00 = ib[y0 * Wi + x0], v01 = ib[y0 * Wi + x0 + 1];
    const float v10 = ib[(y0 + 1) * Wi + x0], v11 = ib[(y0 + 1) * Wi + x0 + 1];
    const float r0 = v00 * (1.0f - wy) + v10 * wy;
    const float r1 = v01 * (1.0f - wy) + v11 * wy;
    out[((size_t)b * Ctot + cb + c) * Ho * Wo + p] = r0 * (1.0f - wx) + r1 * wx;
  }
}

__global__ __launch_bounds__(256) void conv5_splitk(
    const float* __restrict__ in, const float* __restrict__ w,
    float* __restrict__ out, int Cin, int Hi, int Wi, int cChunk) {
  const int b = blockIdx.z;
  const int c0 = blockIdx.y * cChunk;
  const int c1 = min(c0 + cChunk, Cin);
  const int pix = blockIdx.x * blockDim.x + threadIdx.x;
  if (pix >= Hi * Wi) return;
  const int oy = pix / Wi, ox = pix - oy * Wi;
  float acc0 = 0.0f, acc1 = 0.0f;
  const size_t hw = (size_t)Hi * Wi;
  for (int ci = c0; ci < c1; ++ci) {
    const float* inc = in + ((size_t)b * Cin + ci) * hw;
    const float* wc0 = w + (size_t)ci * 25;
    const float* wc1 = w + ((size_t)Cin + ci) * 25;
#pragma unroll
    for (int kh = 0; kh < 5; ++kh) {
      const int iy = oy - 2 + kh;
      if (iy < 0 || iy >= Hi) continue;
#pragma unroll
      for (int kw = 0; kw < 5; ++kw) {
        const int ix = ox - 2 + kw;
        if (ix < 0 || ix >= Wi) continue;
        const float v = inc[iy * Wi + ix];
        acc0 = fmaf(wc0[kh * 5 + kw], v, acc0);
        acc1 = fmaf(wc1[kh * 5 + kw], v, acc1);
      }
    }
  }
  const size_t o = (size_t)b * 2 * hw + pix;
  atomicAdd(&out[o], acc0);
  atomicAdd(&out[o + hw], acc1);
}

static inline int cdiv(int a, int b) { return (a + b - 1) / b; }

extern "C" void kernel_launch(void* const* d_in, const int* in_sizes, int n_in,
                              void* d_out, int out_size, void* d_ws, size_t ws_size,
                              hipStream_t stream) {
  (void)in_sizes; (void)n_in; (void)out_size; (void)ws_size;
  const float* im1     = (const float*)d_in[0];
  const float* im2     = (const float*)d_in[1];
  const float* wA1     = (const float*)d_in[2];
  const float* wA2     = (const float*)d_in[3];
  const float* wA3     = (const float*)d_in[4];
  const float* wB1     = (const float*)d_in[5];
  const float* wB2     = (const float*)d_in[6];
  const float* wB3     = (const float*)d_in[7];
  const float* w_redir = (const float*)d_in[8];
  const float* b_redir = (const float*)d_in[9];
  const float* w3_1    = (const float*)d_in[10];
  const float* w4      = (const float*)d_in[11];
  const float* w4_1    = (const float*)d_in[12];
  const float* w5      = (const float*)d_in[13];
  const float* w5_1    = (const float*)d_in[14];
  const float* w6      = (const float*)d_in[15];
  const float* wd5     = (const float*)d_in[16];
  const float* wd4     = (const float*)d_in[17];
  const float* wd3     = (const float*)d_in[18];
  const float* wd2     = (const float*)d_in[19];
  const float* wf5     = (const float*)d_in[20];
  const float* wf4     = (const float*)d_in[21];
  const float* wf3     = (const float*)d_in[22];
  const float* wpred   = (const float*)d_in[23];

  char* wsb = (char*)d_ws;
  auto at = [&](size_t byte_off) -> void* { return wsb + byte_off; };
  const int B = 4;

  // ======== Explicit memory map (total 184.0 MB) ==========================
  // R0 [0, 39,337,984): T1 bf16 hi/lo [4,196,196,64]   (phases 1-3)
  //     -> overlaid by w41/w5/w51 packed weights        (phase 4+)
  // R1 [39,337,984, 59,817,984): C2 hi/lo [4,100,100,128] -> w6 packed
  // R2 [59,817,984, 117,569,536): TA,TB,CORRA,Xh/l,X2h/l -> decoder buffers
  // R3.. : T3h/l, X3h/l, T4h/l, X4h/l
  // R7: fp32 persistents A, X2f, X3f, X4f, X5f
  // R8: early packed weights w2A,w2B,w3A,w3B,w31,w4
  u16* T1h = (u16*)at(0);               u16* T1l = (u16*)at(19668992);
  u16* C2h = (u16*)at(39337984);        u16* C2l = (u16*)at(49577984);
  float* TA    = (float*)at(59817984);
  float* TB    = (float*)at(69255168);
  float* CORRA = (float*)at(78692352);
  u16* Xh  = (u16*)at(88129536);        u16* Xl  = (u16*)at(97729536);
  u16* X2h = (u16*)at(107329536);       u16* X2l = (u16*)at(112449536);
  u16* T3h = (u16*)at(117569536);       u16* T3l = (u16*)at(120338432);
  u16* X3h = (u16*)at(123107328);       u16* X3l = (u16*)at(125876224);
  u16* T4h = (u16*)at(128645120);       u16* T4l = (u16*)at(129447936);
  u16* X4h = (u16*)at(130250752);       u16* X4l = (u16*)at(131053568);
  float* A   = (float*)at(131856384);   // [4,128,96,96] NCHW, decoder lvl2
  float* X2f = (float*)at(150730752);   // [4,256,48,48]
  float* X3f = (float*)at(160167936);   // [4,512,24,24]
  float* X4f = (float*)at(164886528);   // [4,512,12,12]
  float* X5f = (float*)at(166066176);   // [4,1024,6,6]
  // early packed weights
  u16* w2Ahp = (u16*)at(166656000);     u16* w2Alp = (u16*)at(167065600);
  u16* w2Bhp = (u16*)at(167475200);     u16* w2Blp = (u16*)at(167884800);
  u16* w3Ahp = (u16*)at(168294400);     u16* w3Alp = (u16*)at(169932800);
  u16* w3Bhp = (u16*)at(171571200);     u16* w3Blp = (u16*)at(173209600);
  u16* w31hp = (u16*)at(174848000);     u16* w31lp = (u16*)at(177059840);
  u16* w4hp  = (u16*)at(179271680);     u16* w4lp  = (u16*)at(181630976);
  // late packed weights (overlay R0/R1 after T1/C2 dead)
  u16* w41hp = (u16*)at(0);             u16* w41lp = (u16*)at(4718592);
  u16* w5hp  = (u16*)at(9437184);       u16* w5lp  = (u16*)at(14155776);
  u16* w51hp = (u16*)at(18874368);      u16* w51lp = (u16*)at(23592960);
  u16* w6hp  = (u16*)at(39337984);      u16* w6lp  = (u16*)at(48775168);
  // decoder buffers (overlay R2 after encoder)
  float* Y5   = (float*)at(59817984);   // [4,1024,12,12]
  float* F5   = (float*)at(62177280);
  float* Y4   = (float*)at(62182144);   // [4,770,24,24]
  float* F4   = (float*)at(69278464);
  float* Y3   = (float*)at(69297152);   // [4,386,48,48]
  float* F3   = (float*)at(83526656);
  float* Y2   = (float*)at(83600384);   // [4,194,96,96]
  float* PRED = (float*)at(112206848);  // [4,2,96,96], ends 112,501,760

  auto pack = [&](const float* w, u16* hi, u16* lo, int O, int Ci, int Cip,
                  int KH, int KW) {
    long total = (long)O * Cip * KH * KW;
    pack_w<<<dim3((unsigned)((total + 255) / 256)), 256, 0, stream>>>(
        w, hi, lo, O, Ci, Cip, KH, KW);
  };
  auto halo = [&](u16* hi, u16* lo, int H, int W, int pad, int C, int Hp, int Wp) {
    long total = (long)Hp * Wp * C;
    halo_fill<<<dim3((unsigned)((total + 255) / 256), B), 256, 0, stream>>>(
        hi, lo, H, W, pad, C, Hp, Wp);
  };

  // ---- 1. early weight packs ----
  pack(wA2, w2Ahp, w2Alp, 128, 64, 64, 5, 5);
  pack(wB2, w2Bhp, w2Blp, 128, 64, 64, 5, 5);
  pack(wA3, w3Ahp, w3Alp, 256, 128, 128, 5, 5);
  pack(wB3, w3Bhp, w3Blp, 256, 128, 128, 5, 5);
  pack(w3_1, w31hp, w31lp, 256, 473, 480, 3, 3);
  pack(w4, w4hp, w4lp, 512, 256, 256, 3, 3);

  // ---- 2. branch A: conv1A -> conv2A -> conv3A ----
  { dim3 g(cdiv(192 * 192, 256), 8, B);
    conv_direct_nhwc<7, 8><<<g, 256, 0, stream>>>(
        im1, wA1, nullptr, T1h, T1l, 3, 384, 384, 192, 192, 2, 3,
        64, 196, 196, 2, 0); }
  halo(T1h, T1l, 192, 192, 2, 64, 196, 196);
  { GemmP P{};  // conv2A: 64ch@192 -> 128ch@96; outputs A(fp32 NCHW) + C2 bf16
    P.Ah = w2Ahp; P.Al = w2Alp; P.Bh = T1h; P.Bl = T1l;
    P.C = A; P.Nh = C2h; P.Nl = C2l;
    P.M = 128; P.N = B * 96 * 96; P.K = 1600; P.Cip = 64;
    P.Ho = 96; P.Wo = 96; P.HoWo = 9216; P.stride = 2; P.KW = 5;
    P.Hp = 196; P.Wp = 196; P.Hp2 = 100; P.Wp2 = 100; P.pad2 = 2;
    gemm_conv<<<dim3(288, 1), 256, 0, stream>>>(P); }
  halo(C2h, C2l, 96, 96, 2, 128, 100, 100);
  { GemmP P{};  // conv3A: 128ch@96 -> 256ch@48; outputs TA(fp32 NHWC) + CORRA
    P.Ah = w3Ahp; P.Al = w3Alp; P.Bh = C2h; P.Bl = C2l;
    P.C = CORRA; P.F = TA;
    P.M = 256; P.N = B * 48 * 48; P.K = 3200; P.Cip = 128;
    P.Ho = 48; P.Wo = 48; P.HoWo = 2304; P.stride = 2; P.KW = 5;
    P.Hp = 100; P.Wp = 100;
    gemm_conv<<<dim3(72, 2), 256, 0, stream>>>(P); }

  // ---- 3. branch B (reuses T1/C2) ----
  { dim3 g(cdiv(192 * 192, 256), 8, B);
    conv_direct_nhwc<7, 8><<<g, 256, 0, stream>>>(
        im2, wB1, nullptr, T1h, T1l, 3, 384, 384, 192, 192, 2, 3,
        64, 196, 196, 2, 0); }
  halo(T1h, T1l, 192, 192, 2, 64, 196, 196);
  { GemmP P{};  // conv2B
    P.Ah = w2Bhp; P.Al = w2Blp; P.Bh = T1h; P.Bl = T1l;
    P.Nh = C2h; P.Nl = C2l;
    P.M = 128; P.N = B * 96 * 96; P.K = 1600; P.Cip = 64;
    P.Ho = 96; P.Wo = 96; P.HoWo = 9216; P.stride = 2; P.KW = 5;
    P.Hp = 196; P.Wp = 196; P.Hp2 = 100; P.Wp2 = 100; P.pad2 = 2;
    gemm_conv<<<dim3(288, 1), 256, 0, stream>>>(P); }
  halo(C2h, C2l, 96, 96, 2, 128, 100, 100);
  { GemmP P{};  // conv3B -> TB only
    P.Ah = w3Bhp; P.Al = w3Blp; P.Bh = C2h; P.Bl = C2l;
    P.F = TB;
    P.M = 256; P.N = B * 48 * 48; P.K = 3200; P.Cip = 128;
    P.Ho = 48; P.Wo = 48; P.HoWo = 2304; P.stride = 2; P.KW = 5;
    P.Hp = 100; P.Wp = 100;
    gemm_conv<<<dim3(72, 2), 256, 0, stream>>>(P); }

  // ---- 4. late weight packs (T1/C2 now dead) ----
  pack(w4_1, w41hp, w41lp, 512, 512, 512, 3, 3);
  pack(w5, w5hp, w5lp, 512, 512, 512, 3, 3);
  pack(w5_1, w51hp, w51lp, 512, 512, 512, 3, 3);
  pack(w6, w6hp, w6lp, 1024, 512, 512, 3, 3);

  // ---- 5. redir + correlation -> X (NHWC bf16, Cip=480, pad 1) ----
  { dim3 g(cdiv(48 * 48, 256), 4, B);
    conv_direct_nhwc<1, 8><<<g, 256, 0, stream>>>(
        CORRA, w_redir, b_redir, Xh, Xl, 256, 48, 48, 48, 48, 1, 0,
        480, 50, 50, 1, 441); }
  { dim3 g(2304, B);
    corr_kernel<<<g, 256, 0, stream>>>(TA, TB, Xh, Xl); }
  halo(Xh, Xl, 48, 48, 1, 480, 50, 50);  // ch 473..479: poison * zero-weight = 0

  // ---- 6. encoder GEMMs ----
  { GemmP P{};  // w3_1: 473(480)->256 @48
    P.Ah = w31hp; P.Al = w31lp; P.Bh = Xh; P.Bl = Xl;
    P.C = X2f; P.Nh = X2h; P.Nl = X2l;
    P.M = 256; P.N = 9216; P.K = 4320; P.Cip = 480;
    P.Ho = 48; P.Wo = 48; P.HoWo = 2304; P.stride = 1; P.KW = 3;
    P.Hp = 50; P.Wp = 50; P.Hp2 = 50; P.Wp2 = 50; P.pad2 = 1;
    gemm_conv<<<dim3(72, 2), 256, 0, stream>>>(P); }
  halo(X2h, X2l, 48, 48, 1, 256, 50, 50);
  { GemmP P{};  // w4: 256->512, s2, 48->24
    P.Ah = w4hp; P.Al = w4lp; P.Bh = X2h; P.Bl = X2l;
    P.Nh = T3h; P.Nl = T3l;
    P.M = 512; P.N = 2304; P.K = 2304; P.Cip = 256;
    P.Ho = 24; P.Wo = 24; P.HoWo = 576; P.stride = 2; P.KW = 3;
    P.Hp = 50; P.Wp = 50; P.Hp2 = 26; P.Wp2 = 26; P.pad2 = 1;
    gemm_conv<<<dim3(18, 4), 256, 0, stream>>>(P); }
  halo(T3h, T3l, 24, 24, 1, 512, 26, 26);
  { GemmP P{};  // w4_1: 512->512 @24
    P.Ah = w41hp; P.Al = w41lp; P.Bh = T3h; P.Bl = T3l;
    P.C = X3f; P.Nh = X3h; P.Nl = X3l;
    P.M = 512; P.N = 2304; P.K = 4608; P.Cip = 512;
    P.Ho = 24; P.Wo = 24; P.HoWo = 576; P.stride = 1; P.KW = 3;
    P.Hp = 26; P.Wp = 26; P.Hp2 = 26; P.Wp2 = 26; P.pad2 = 1;
    gemm_conv<<<dim3(18, 4), 256, 0, stream>>>(P); }
  halo(X3h, X3l, 24, 24, 1, 512, 26, 26);
  { GemmP P{};  // w5: 512->512, s2, 24->12
    P.Ah = w5hp; P.Al = w5lp; P.Bh = X3h; P.Bl = X3l;
    P.Nh = T4h; P.Nl = T4l;
    P.M = 512; P.N = 576; P.K = 4608; P.Cip = 512;
    P.Ho = 12; P.Wo = 12; P.HoWo = 144; P.stride = 2; P.KW = 3;
    P.Hp = 26; P.Wp = 26; P.Hp2 = 14; P.Wp2 = 14; P.pad2 = 1;
    gemm_conv<<<dim3(5, 4), 256, 0, stream>>>(P); }
  halo(T4h, T4l, 12, 12, 1, 512, 14, 14);
  { GemmP P{};  // w5_1: 512->512 @12
    P.Ah = w51hp; P.Al = w51lp; P.Bh = T4h; P.Bl = T4l;
    P.C = X4f; P.Nh = X4h; P.Nl = X4l;
    P.M = 512; P.N = 576; P.K = 4608; P.Cip = 512;
    P.Ho = 12; P.Wo = 12; P.HoWo = 144; P.stride = 1; P.KW = 3;
    P.Hp = 14; P.Wp = 14; P.Hp2 = 14; P.Wp2 = 14; P.pad2 = 1;
    gemm_conv<<<dim3(5, 4), 256, 0, stream>>>(P); }
  halo(X4h, X4l, 12, 12, 1, 512, 14, 14);
  { GemmP P{};  // w6: 512->1024, s2, 12->6
    P.Ah = w6hp; P.Al = w6lp; P.Bh = X4h; P.Bl = X4l;
    P.C = X5f;
    P.M = 1024; P.N = 144; P.K = 4608; P.Cip = 512;
    P.Ho = 6; P.Wo = 6; P.HoWo = 36; P.stride = 2; P.KW = 3;
    P.Hp = 14; P.Wp = 14;
    gemm_conv<<<dim3(2, 8), 256, 0, stream>>>(P); }

  // ---- 7. decoder (fp32; buffers overlay dead R2) ----
  { dim3 g(cdiv(512 * 36, 256), B);  upconv_kernel<<<g, 256, 0, stream>>>(X5f, wd5, Y5, 1024, 512, 6, 6, 1024, 0); }
  { dim3 g(cdiv(512 * 144, 256), B); copy_ch<<<g, 256, 0, stream>>>(X4f, Y5, 512, 144, 1024, 512); }
  hipMemsetAsync(F5, 0, 1152 * sizeof(float), stream);
  { dim3 g(cdiv(144, 64), cdiv(1024, 64), B); conv5_splitk<<<g, 64, 0, stream>>>(Y5, wf5, F5, 1024, 12, 12, 64); }

  { dim3 g(cdiv(256 * 144, 256), B); upconv_kernel<<<g, 256, 0, stream>>>(Y5, wd4, Y4, 1024, 256, 12, 12, 770, 0); }
  { dim3 g(cdiv(512 * 576, 256), B); copy_ch<<<g, 256, 0, stream>>>(X3f, Y4, 512, 576, 770, 256); }
  { dim3 g(cdiv(2 * 576, 256), B);   upsample_bilinear<<<g, 256, 0, stream>>>(F5, Y4, 2, 12, 12, 24, 24, 770, 768); }
  hipMemsetAsync(F4, 0, 4608 * sizeof(float), stream);
  { dim3 g(cdiv(576, 64), cdiv(770, 64), B); conv5_splitk<<<g, 64, 0, stream>>>(Y4, wf4, F4, 770, 24, 24, 64); }

  { dim3 g(cdiv(128 * 576, 256), B);  upconv_kernel<<<g, 256, 0, stream>>>(Y4, wd3, Y3, 770, 128, 24, 24, 386, 0); }
  { dim3 g(cdiv(256 * 2304, 256), B); copy_ch<<<g, 256, 0, stream>>>(X2f, Y3, 256, 2304, 386, 128); }
  { dim3 g(cdiv(2 * 2304, 256), B);   upsample_bilinear<<<g, 256, 0, stream>>>(F4, Y3, 2, 24, 24, 48, 48, 386, 384); }
  hipMemsetAsync(F3, 0, 18432 * sizeof(float), stream);
  { dim3 g(cdiv(2304, 256), cdiv(386, 64), B); conv5_splitk<<<g, 256, 0, stream>>>(Y3, wf3, F3, 386, 48, 48, 64); }

  { dim3 g(cdiv(64 * 2304, 256), B);  upconv_kernel<<<g, 256, 0, stream>>>(Y3, wd2, Y2, 386, 64, 48, 48, 194, 0); }
  { dim3 g(cdiv(128 * 9216, 256), B); copy_ch<<<g, 256, 0, stream>>>(A, Y2, 128, 9216, 194, 64); }
  { dim3 g(cdiv(2 * 9216, 256), B);   upsample_bilinear<<<g, 256, 0, stream>>>(F3, Y2, 2, 48, 48, 96, 96, 194, 192); }
  hipMemsetAsync(PRED, 0, 73728 * sizeof(float), stream);
  { dim3 g(cdiv(9216, 256), cdiv(194, 64), B); conv5_splitk<<<g, 256, 0, stream>>>(Y2, wpred, PRED, 194, 96, 96, 64); }

  { dim3 g(cdiv(2 * 384 * 384, 256), B);
    upsample_bilinear<<<g, 256, 0, stream>>>(PRED, (float*)d_out, 2, 96, 96, 384, 384, 2, 0); }
}

// Round 10
// 4192.669 us; speedup vs baseline: 1.7878x; 1.1831x over previous
//
#include <hip/hip_runtime.h>
#include <hip/hip_bf16.h>

// ---------------------------------------------------------------------------
// FlowNetC forward, MI355X. Round 10: (verified R9 base) + row-ownership
// correlation, conv1 OCPT=16, tile-64 GEMM variant for the occupancy-starved
// encoder tail. Memory map unchanged (184 MB).
// ---------------------------------------------------------------------------

typedef unsigned short u16;
typedef __attribute__((ext_vector_type(8))) short short8;
typedef __attribute__((ext_vector_type(4))) float f32x4;

__device__ __forceinline__ int reflect_idx(int i, int n) {
  if (i < 0) i = -i;
  if (i >= n) i = 2 * n - 2 - i;
  return i;
}

__device__ __forceinline__ u16 f2bf(float f) {       // RTN-even fp32 -> bf16
  unsigned u = __float_as_uint(f);
  u += 0x7FFFu + ((u >> 16) & 1u);
  return (u16)(u >> 16);
}
__device__ __forceinline__ float bf2f(u16 h) {
  return __uint_as_float((unsigned)h << 16);
}

typedef __attribute__((address_space(1))) const unsigned int gu32;
typedef __attribute__((address_space(3))) unsigned int lu32;
__device__ __forceinline__ void gload16(const void* g, void* l) {
  __builtin_amdgcn_global_load_lds((gu32*)g, (lu32*)l, 16, 0, 0);
}

// ---------------------------------------------------------------------------
// Weight pack: w[O][Ci][KH][KW] fp32 -> hi/lo bf16 [O][K], K=(kh*KW+kw)*Cip+ci.
// ---------------------------------------------------------------------------
__global__ __launch_bounds__(256) void pack_w(
    const float* __restrict__ w, u16* __restrict__ hi, u16* __restrict__ lo,
    int O, int Ci, int Cip, int KH, int KW) {
  const long K = (long)Cip * KH * KW;
  const long total = (long)O * K;
  long idx = (long)blockIdx.x * 256 + threadIdx.x;
  if (idx >= total) return;
  const int o = (int)(idx / K);
  const long k = idx - (long)o * K;
  const int q = (int)(k / Cip), ci = (int)(k - (long)q * Cip);
  const int kh = q / KW, kw = q - kh * KW;
  const float v = (ci < Ci) ? w[(((size_t)o * Ci + ci) * KH + kh) * KW + kw] : 0.f;
  const u16 h = f2bf(v);
  hi[idx] = h;
  lo[idx] = f2bf(v - bf2f(h));
}

// ---------------------------------------------------------------------------
// Direct conv (fp32) writing bf16 hi/lo NHWC into padded buffer interior.
// conv1 (Ci=3) and redir (1x1). Reflect pad, ReLU.
// ---------------------------------------------------------------------------
template <int K, int OCPT>
__global__ __launch_bounds__(256) void conv_direct_nhwc(
    const float* __restrict__ in, const float* __restrict__ w,
    const float* __restrict__ bias, u16* __restrict__ outhi,
    u16* __restrict__ outlo, int Cin, int Hi, int Wi, int Ho, int Wo,
    int stride, int pad, int Cip, int Hp, int Wp, int pad2, int cb) {
  const int pix = blockIdx.x * blockDim.x + threadIdx.x;
  if (pix >= Ho * Wo) return;
  const int b = blockIdx.z;
  const int oc0 = blockIdx.y * OCPT;
  const int oy = pix / Wo, ox = pix - oy * Wo;
  const int iy0 = oy * stride - pad, ix0 = ox * stride - pad;
  int iys[K], ixs[K];
#pragma unroll
  for (int k = 0; k < K; ++k) {
    iys[k] = reflect_idx(iy0 + k, Hi);
    ixs[k] = reflect_idx(ix0 + k, Wi);
  }
  float acc[OCPT];
#pragma unroll
  for (int o = 0; o < OCPT; ++o) acc[o] = bias ? bias[oc0 + o] : 0.0f;
  const size_t hw = (size_t)Hi * Wi;
  const float* inb = in + (size_t)b * Cin * hw;
  const int wstride = Cin * K * K;
  for (int ci = 0; ci < Cin; ++ci) {
    const float* inc = inb + (size_t)ci * hw;
    const float* wc = w + (size_t)oc0 * wstride + (size_t)ci * (K * K);
#pragma unroll
    for (int kh = 0; kh < K; ++kh) {
      const float* inr = inc + iys[kh] * Wi;
#pragma unroll
      for (int kw = 0; kw < K; ++kw) {
        const float v = inr[ixs[kw]];
#pragma unroll
        for (int o = 0; o < OCPT; ++o)
          acc[o] = fmaf(wc[(size_t)o * wstride + kh * K + kw], v, acc[o]);
      }
    }
  }
  const size_t o2 = ((size_t)(b * Hp + oy + pad2) * Wp + ox + pad2) * Cip + cb + oc0;
#pragma unroll
  for (int o = 0; o < OCPT; ++o) {
    const float r = fmaxf(acc[o], 0.0f);
    const u16 h = f2bf(r);
    outhi[o2 + o] = h;
    outlo[o2 + o] = f2bf(r - bf2f(h));
  }
}

// ---------------------------------------------------------------------------
// Reflect-pad halo fill for NHWC bf16 buffers.
// ---------------------------------------------------------------------------
__global__ __launch_bounds__(256) void halo_fill(
    u16* __restrict__ hi, u16* __restrict__ lo,
    int H, int W, int pad, int C, int Hp, int Wp) {
  const int b = blockIdx.y;
  const long idx = (long)blockIdx.x * 256 + threadIdx.x;
  if (idx >= (long)Hp * Wp * C) return;
  const int c = (int)(idx % C);
  const int cell = (int)(idx / C);
  const int x = cell % Wp, y = cell / Wp;
  if (y >= pad && y < H + pad && x >= pad && x < W + pad) return;
  const int sy = pad + reflect_idx(y - pad, H);
  const int sx = pad + reflect_idx(x - pad, W);
  const size_t dst = ((size_t)(b * Hp + y) * Wp + x) * C + c;
  const size_t src = ((size_t)(b * Hp + sy) * Wp + sx) * C + c;
  hi[dst] = hi[src];
  lo[dst] = lo[src];
}

// ---------------------------------------------------------------------------
// Correlation v2 (row-ownership). Block = 4x4 output-pixel tile; tB tile
// (16x256 fp32) staged in LDS; each thread owns tA rows of the 24x24 union
// window, streams them contiguously, and contributes to all 16 pixels.
// corr(p,off) = dot(tA[p+off], tB[p]) -- exactly one row per output, so
// row-ownership covers every (p,off) exactly once; OOB rows write zeros
// (matches reference zero-padding). Output: X NHWC bf16 hi/lo (480ch,pad 1).
// ---------------------------------------------------------------------------
__global__ __launch_bounds__(256) void corr_kernel(
    const float* __restrict__ tA, const float* __restrict__ tB,
    u16* __restrict__ Xh, u16* __restrict__ Xl) {
  const int W = 48, HW = 2304;
  const int b = blockIdx.y;
  const int tile = blockIdx.x;               // 0..143
  const int i0 = (tile / 12) * 4, j0 = (tile % 12) * 4;
  __shared__ float sB[16 * 256];
  for (int f = threadIdx.x; f < 1024; f += 256) {     // float4 index
    const int p = f >> 6, c4 = f & 63;
    const int pi = p >> 2, pj = p & 3;
    *(float4*)&sB[p * 256 + c4 * 4] =
        *(const float4*)&tB[((size_t)b * HW + (i0 + pi) * W + j0 + pj) * 256 + c4 * 4];
  }
  __syncthreads();
  const float4* sB4 = (const float4*)sB;
  for (int s = threadIdx.x; s < 576; s += 256) {
    const int ri = s / 24, rj = s - ri * 24;
    const int gi = i0 - 10 + ri, gj = j0 - 10 + rj;
    float acc[16];
#pragma unroll
    for (int p = 0; p < 16; ++p) acc[p] = 0.f;
    if (gi >= 0 && gi < 48 && gj >= 0 && gj < 48) {
      const float4* a4 = (const float4*)&tA[((size_t)b * HW + gi * W + gj) * 256];
#pragma unroll 4
      for (int c4 = 0; c4 < 64; ++c4) {
        const float4 av = a4[c4];
#pragma unroll
        for (int p = 0; p < 16; ++p) {
          const float4 bv = sB4[p * 64 + c4];
          acc[p] = fmaf(av.x, bv.x,
                   fmaf(av.y, bv.y, fmaf(av.z, bv.z, fmaf(av.w, bv.w, acc[p]))));
        }
      }
    }
#pragma unroll
    for (int pi = 0; pi < 4; ++pi) {
      const int di = ri - 10 - pi;
      if (di < -10 || di > 10) continue;
#pragma unroll
      for (int pj = 0; pj < 4; ++pj) {
        const int dj = rj - 10 - pj;
        if (dj < -10 || dj > 10) continue;
        const int off = (di + 10) * 21 + (dj + 10);
        const float v = acc[pi * 4 + pj];
        const size_t o =
            ((size_t)(b * 50 + i0 + pi + 1) * 50 + (j0 + pj + 1)) * 480 + off;
        const u16 h = f2bf(v);
        Xh[o] = h;
        Xl[o] = f2bf(v - bf2f(h));
      }
    }
  }
}

// ---------------------------------------------------------------------------
// Implicit-GEMM MFMA conv, templated tile T (T x T, 4 waves 2x2, BK=32).
// T=128: 4x4 frags/wave, 2 loads/thread/buffer. T=64: 2x2 frags, 1 load.
// bf16 hi/lo split (3 MFMAs / k-step), fp32 accumulate, fused ReLU epilogue.
// ---------------------------------------------------------------------------
struct GemmP {
  const u16 *Ah, *Al, *Bh, *Bl;
  float *C;                     // fp32 NCHW out (opt)
  float *F;                     // fp32 NHWC out, unpadded (opt)
  u16 *Nh, *Nl;                 // bf16 NHWC padded out (opt)
  int M, N, K, Cip, Ho, Wo, HoWo, stride, KW, Hp, Wp;
  int Hp2, Wp2, pad2;
};

template <int T>
__global__ __launch_bounds__(256) void gemm_conv(GemmP g) {
  constexpr int NF = T / 32;        // fragments per wave dim
  constexpr int NL = T / 64;        // 16B loads per thread per buffer
  constexpr int HALF = T / 2;
  const int tid = threadIdx.x;
  const int lane = tid & 63, wid = tid >> 6;
  const int wr = wid >> 1, wc = wid & 1;
  const int n0 = blockIdx.x * T, m0 = blockIdx.y * T;

  __shared__ __align__(16) u16 sAh[T * 32], sAl[T * 32], sBh[T * 32], sBl[T * 32];

  // staging slots: s = i*256 + tid; kgroup = s/T, row = s%T
  size_t aoff[NL], boff[NL];
#pragma unroll
  for (int i = 0; i < NL; ++i) {
    const int s = i * 256 + tid, gs = s / T, r = s % T;
    aoff[i] = (size_t)(m0 + r) * g.K + gs * 8;
    int n = n0 + r;
    if (n >= g.N) n = g.N - 1;
    const int b = n / g.HoWo, p = n - b * g.HoWo;
    const int oy = p / g.Wo, ox = p - oy * g.Wo;
    boff[i] = ((size_t)(b * g.Hp + oy * g.stride) * g.Wp + ox * g.stride) * (size_t)g.Cip + gs * 8;
  }

  f32x4 acc[NF][NF];
#pragma unroll
  for (int m = 0; m < NF; ++m)
#pragma unroll
    for (int n = 0; n < NF; ++n) acc[m][n] = f32x4{0.f, 0.f, 0.f, 0.f};

  int ci0 = 0, kwc = 0, khw_off = 0;                 // khw_off = (kh*Wp+kw)*Cip
  const int rowAdd = (g.Wp - (g.KW - 1)) * g.Cip;
  for (int k0 = 0; k0 < g.K; k0 += 32) {
    const size_t ka = (size_t)k0;
    const size_t kb = (size_t)khw_off + ci0;
    __syncthreads();
#pragma unroll
    for (int i = 0; i < NL; ++i) {
      const int lo_ = (i * 256 + wid * 64) * 8;      // u16 offset, wave-uniform
      gload16(g.Ah + aoff[i] + ka, &sAh[lo_]);
      gload16(g.Al + aoff[i] + ka, &sAl[lo_]);
      gload16(g.Bh + boff[i] + kb, &sBh[lo_]);
      gload16(g.Bl + boff[i] + kb, &sBl[lo_]);
    }
    __syncthreads();

    const int fr = lane & 15, fs = (lane >> 4) * T;
    short8 ah[NF], al[NF], bh[NF], bl[NF];
#pragma unroll
    for (int m = 0; m < NF; ++m) {
      const int ra = (fs + wr * HALF + m * 16 + fr) * 8;
      ah[m] = *(const short8*)&sAh[ra];
      al[m] = *(const short8*)&sAl[ra];
      const int rb = (fs + wc * HALF + m * 16 + fr) * 8;
      bh[m] = *(const short8*)&sBh[rb];
      bl[m] = *(const short8*)&sBl[rb];
    }
#pragma unroll
    for (int m = 0; m < NF; ++m)
#pragma unroll
      for (int n = 0; n < NF; ++n) {
        acc[m][n] = __builtin_amdgcn_mfma_f32_16x16x32_bf16(ah[m], bh[n], acc[m][n], 0, 0, 0);
        acc[m][n] = __builtin_amdgcn_mfma_f32_16x16x32_bf16(ah[m], bl[n], acc[m][n], 0, 0, 0);
        acc[m][n] = __builtin_amdgcn_mfma_f32_16x16x32_bf16(al[m], bh[n], acc[m][n], 0, 0, 0);
      }
    ci0 += 32;
    if (ci0 >= g.Cip) {
      ci0 = 0;
      ++kwc;
      if (kwc == g.KW) { kwc = 0; khw_off += rowAdd; }
      else khw_off += g.Cip;
    }
  }

  // epilogue: C/D layout col=lane&15 (pixel), row=(lane>>4)*4+j (oc)
  const int colL = lane & 15, rg = (lane >> 4) * 4;
#pragma unroll
  for (int n = 0; n < NF; ++n) {
    const int np = n0 + wc * HALF + n * 16 + colL;
    if (np >= g.N) continue;
    const int b = np / g.HoWo, p = np - b * g.HoWo;
    const int oy = p / g.Wo, ox = p - oy * g.Wo;
#pragma unroll
    for (int m = 0; m < NF; ++m) {
      const int oc0 = m0 + wr * HALF + m * 16 + rg;
      float vv[4];
#pragma unroll
      for (int j = 0; j < 4; ++j) vv[j] = fmaxf(acc[m][n][j], 0.0f);
      if (g.C) {
        const size_t base = ((size_t)b * g.M + oc0) * g.HoWo + p;
#pragma unroll
        for (int j = 0; j < 4; ++j) g.C[base + (size_t)j * g.HoWo] = vv[j];
      }
      if (g.F) {
        float4 f4 = {vv[0], vv[1], vv[2], vv[3]};
        *(float4*)&g.F[((size_t)b * g.HoWo + p) * g.M + oc0] = f4;
      }
      if (g.Nh) {
        const size_t a2 =
            ((size_t)(b * g.Hp2 + oy + g.pad2) * g.Wp2 + ox + g.pad2) * (size_t)g.M + oc0;
        ushort4 h4, l4;
        h4.x = f2bf(vv[0]); h4.y = f2bf(vv[1]); h4.z = f2bf(vv[2]); h4.w = f2bf(vv[3]);
        l4.x = f2bf(vv[0] - bf2f(h4.x)); l4.y = f2bf(vv[1] - bf2f(h4.y));
        l4.z = f2bf(vv[2] - bf2f(h4.z)); l4.w = f2bf(vv[3] - bf2f(h4.w));
        *(ushort4*)&g.Nh[a2] = h4;
        *(ushort4*)&g.Nl[a2] = l4;
      }
    }
  }
}

// ---------------------------------------------------------------------------
// Decoder kernels (fp32, verified)
// ---------------------------------------------------------------------------
__global__ __launch_bounds__(256) void upconv_kernel(
    const float* __restrict__ x, const float* __restrict__ w,
    float* __restrict__ y, int Cin, int Cout, int H, int W, int Ctot, int cb) {
  const int b = blockIdx.y;
  const int hw = H * W;
  const int total = Cout * hw;
  const int idx = blockIdx.x * blockDim.x + threadIdx.x;
  if (idx >= total) return;
  const int oc = idx / hw;
  const int p = idx - oc * hw;
  const int h = p / W, wx = p - h * W;
  const float* xb = x + (size_t)b * Cin * hw + p;
  float acc = 0.0f;
  for (int ci = 0; ci < Cin; ++ci)
    acc = fmaf(xb[(size_t)ci * hw], w[(size_t)ci * Cout + oc], acc);
  const float r = fmaxf(acc, 0.0f);
  const int Wo = 2 * W;
  float* yp = y + (((size_t)b * Ctot + cb + oc) * (2 * H) + 2 * h) * Wo + 2 * wx;
  yp[0] = r; yp[1] = 0.0f; yp[Wo] = 0.0f; yp[Wo + 1] = 0.0f;
}

__global__ __launch_bounds__(256) void copy_ch(
    const float* __restrict__ src, float* __restrict__ dst,
    int Cs, int HW, int Ctot, int cb) {
  const int b = blockIdx.y;
  const int total = Cs * HW;
  for (int idx = blockIdx.x * blockDim.x + threadIdx.x; idx < total;
       idx += gridDim.x * blockDim.x) {
    const int c = idx / HW, p = idx - (idx / HW) * HW;
    dst[((size_t)b * Ctot + cb + c) * HW + p] = src[((size_t)b * Cs + c) * HW + p];
  }
}

__global__ __launch_bounds__(256) void upsample_bilinear(
    const float* __restrict__ in, float* __restrict__ out,
    int C, int Hi, int Wi, int Ho, int Wo, int Ctot, int cb) {
  const int b = blockIdx.y;
  const int total = C * Ho * Wo;
  const float sh = (float)(Hi - 1) / (float)(Ho - 1);
  const float sw = (float)(Wi - 1) / (float)(Wo - 1);
  for (int idx = blockIdx.x * blockDim.x + threadIdx.x; idx < total;
       idx += gridDim.x * blockDim.x) {
    const int c = idx / (Ho * Wo);
    const int p = idx - c * (Ho * Wo);
    const int oy = p / Wo, ox = p - oy * Wo;
    const float fy = oy * sh, fx = ox * sw;
    int y0 = (int)fy; if (y0 > Hi - 2) y0 = Hi - 2;
    int x0 = (int)fx; if (x0 > Wi - 2) x0 = Wi - 2;
    const float wy = fy - y0, wx = fx - x0;
    const float* ib = in + ((size_t)b * C + c) * Hi * Wi;
    const float v00 = ib[y0 * Wi + x0], v01 = ib[y0 * Wi + x0 + 1];
    const float v10 = ib[(y0 + 1) * Wi + x0], v11 = ib[(y0 + 1) * Wi + x0 + 1];
    const float r0 = v00 * (1.0f - wy) + v10 * wy;
    const float r1 = v01 * (1.0f - wy) + v11 * wy;
    out[((size_t)b * Ctot + cb + c) * Ho * Wo + p] = r0 * (1.0f - wx) + r1 * wx;
  }
}

__global__ __launch_bounds__(256) void conv5_splitk(
    const float* __restrict__ in, const float* __restrict__ w,
    float* __restrict__ out, int Cin, int Hi, int Wi, int cChunk) {
  const int b = blockIdx.z;
  const int c0 = blockIdx.y * cChunk;
  const int c1 = min(c0 + cChunk, Cin);
  const int pix = blockIdx.x * blockDim.x + threadIdx.x;
  if (pix >= Hi * Wi) return;
  const int oy = pix / Wi, ox = pix - oy * Wi;
  float acc0 = 0.0f, acc1 = 0.0f;
  const size_t hw = (size_t)Hi * Wi;
  for (int ci = c0; ci < c1; ++ci) {
    const float* inc = in + ((size_t)b * Cin + ci) * hw;
    const float* wc0 = w + (size_t)ci * 25;
    const float* wc1 = w + ((size_t)Cin + ci) * 25;
#pragma unroll
    for (int kh = 0; kh < 5; ++kh) {
      const int iy = oy - 2 + kh;
      if (iy < 0 || iy >= Hi) continue;
#pragma unroll
      for (int kw = 0; kw < 5; ++kw) {
        const int ix = ox - 2 + kw;
        if (ix < 0 || ix >= Wi) continue;
        const float v = inc[iy * Wi + ix];
        acc0 = fmaf(wc0[kh * 5 + kw], v, acc0);
        acc1 = fmaf(wc1[kh * 5 + kw], v, acc1);
      }
    }
  }
  const size_t o = (size_t)b * 2 * hw + pix;
  atomicAdd(&out[o], acc0);
  atomicAdd(&out[o + hw], acc1);
}

static inline int cdiv(int a, int b) { return (a + b - 1) / b; }

extern "C" void kernel_launch(void* const* d_in, const int* in_sizes, int n_in,
                              void* d_out, int out_size, void* d_ws, size_t ws_size,
                              hipStream_t stream) {
  (void)in_sizes; (void)n_in; (void)out_size; (void)ws_size;
  const float* im1     = (const float*)d_in[0];
  const float* im2     = (const float*)d_in[1];
  const float* wA1     = (const float*)d_in[2];
  const float* wA2     = (const float*)d_in[3];
  const float* wA3     = (const float*)d_in[4];
  const float* wB1     = (const float*)d_in[5];
  const float* wB2     = (const float*)d_in[6];
  const float* wB3     = (const float*)d_in[7];
  const float* w_redir = (const float*)d_in[8];
  const float* b_redir = (const float*)d_in[9];
  const float* w3_1    = (const float*)d_in[10];
  const float* w4      = (const float*)d_in[11];
  const float* w4_1    = (const float*)d_in[12];
  const float* w5      = (const float*)d_in[13];
  const float* w5_1    = (const float*)d_in[14];
  const float* w6      = (const float*)d_in[15];
  const float* wd5     = (const float*)d_in[16];
  const float* wd4     = (const float*)d_in[17];
  const float* wd3     = (const float*)d_in[18];
  const float* wd2     = (const float*)d_in[19];
  const float* wf5     = (const float*)d_in[20];
  const float* wf4     = (const float*)d_in[21];
  const float* wf3     = (const float*)d_in[22];
  const float* wpred   = (const float*)d_in[23];

  char* wsb = (char*)d_ws;
  auto at = [&](size_t byte_off) -> void* { return wsb + byte_off; };
  const int B = 4;

  // ======== Memory map (unchanged from verified R9, 184 MB) ==============
  u16* T1h = (u16*)at(0);               u16* T1l = (u16*)at(19668992);
  u16* C2h = (u16*)at(39337984);        u16* C2l = (u16*)at(49577984);
  float* TA    = (float*)at(59817984);
  float* TB    = (float*)at(69255168);
  float* CORRA = (float*)at(78692352);
  u16* Xh  = (u16*)at(88129536);        u16* Xl  = (u16*)at(97729536);
  u16* X2h = (u16*)at(107329536);       u16* X2l = (u16*)at(112449536);
  u16* T3h = (u16*)at(117569536);       u16* T3l = (u16*)at(120338432);
  u16* X3h = (u16*)at(123107328);       u16* X3l = (u16*)at(125876224);
  u16* T4h = (u16*)at(128645120);       u16* T4l = (u16*)at(129447936);
  u16* X4h = (u16*)at(130250752);       u16* X4l = (u16*)at(131053568);
  float* A   = (float*)at(131856384);   // [4,128,96,96] NCHW
  float* X2f = (float*)at(150730752);   // [4,256,48,48]
  float* X3f = (float*)at(160167936);   // [4,512,24,24]
  float* X4f = (float*)at(164886528);   // [4,512,12,12]
  float* X5f = (float*)at(166066176);   // [4,1024,6,6]
  u16* w2Ahp = (u16*)at(166656000);     u16* w2Alp = (u16*)at(167065600);
  u16* w2Bhp = (u16*)at(167475200);     u16* w2Blp = (u16*)at(167884800);
  u16* w3Ahp = (u16*)at(168294400);     u16* w3Alp = (u16*)at(169932800);
  u16* w3Bhp = (u16*)at(171571200);     u16* w3Blp = (u16*)at(173209600);
  u16* w31hp = (u16*)at(174848000);     u16* w31lp = (u16*)at(177059840);
  u16* w4hp  = (u16*)at(179271680);     u16* w4lp  = (u16*)at(181630976);
  // late packed weights (overlay R0/R1 after T1/C2 dead)
  u16* w41hp = (u16*)at(0);             u16* w41lp = (u16*)at(4718592);
  u16* w5hp  = (u16*)at(9437184);       u16* w5lp  = (u16*)at(14155776);
  u16* w51hp = (u16*)at(18874368);      u16* w51lp = (u16*)at(23592960);
  u16* w6hp  = (u16*)at(39337984);      u16* w6lp  = (u16*)at(48775168);
  // decoder buffers (overlay R2 after encoder)
  float* Y5   = (float*)at(59817984);
  float* F5   = (float*)at(62177280);
  float* Y4   = (float*)at(62182144);
  float* F4   = (float*)at(69278464);
  float* Y3   = (float*)at(69297152);
  float* F3   = (float*)at(83526656);
  float* Y2   = (float*)at(83600384);
  float* PRED = (float*)at(112206848);

  auto pack = [&](const float* w, u16* hi, u16* lo, int O, int Ci, int Cip,
                  int KH, int KW) {
    long total = (long)O * Cip * KH * KW;
    pack_w<<<dim3((unsigned)((total + 255) / 256)), 256, 0, stream>>>(
        w, hi, lo, O, Ci, Cip, KH, KW);
  };
  auto halo = [&](u16* hi, u16* lo, int H, int W, int pad, int C, int Hp, int Wp) {
    long total = (long)Hp * Wp * C;
    halo_fill<<<dim3((unsigned)((total + 255) / 256), B), 256, 0, stream>>>(
        hi, lo, H, W, pad, C, Hp, Wp);
  };

  // ---- 1. early weight packs ----
  pack(wA2, w2Ahp, w2Alp, 128, 64, 64, 5, 5);
  pack(wB2, w2Bhp, w2Blp, 128, 64, 64, 5, 5);
  pack(wA3, w3Ahp, w3Alp, 256, 128, 128, 5, 5);
  pack(wB3, w3Bhp, w3Blp, 256, 128, 128, 5, 5);
  pack(w3_1, w31hp, w31lp, 256, 473, 480, 3, 3);
  pack(w4, w4hp, w4lp, 512, 256, 256, 3, 3);

  // ---- 2. branch A ----
  { dim3 g(cdiv(192 * 192, 256), 4, B);
    conv_direct_nhwc<7, 16><<<g, 256, 0, stream>>>(
        im1, wA1, nullptr, T1h, T1l, 3, 384, 384, 192, 192, 2, 3,
        64, 196, 196, 2, 0); }
  halo(T1h, T1l, 192, 192, 2, 64, 196, 196);
  { GemmP P{};  // conv2A: 64ch@192 -> 128ch@96
    P.Ah = w2Ahp; P.Al = w2Alp; P.Bh = T1h; P.Bl = T1l;
    P.C = A; P.Nh = C2h; P.Nl = C2l;
    P.M = 128; P.N = B * 96 * 96; P.K = 1600; P.Cip = 64;
    P.Ho = 96; P.Wo = 96; P.HoWo = 9216; P.stride = 2; P.KW = 5;
    P.Hp = 196; P.Wp = 196; P.Hp2 = 100; P.Wp2 = 100; P.pad2 = 2;
    gemm_conv<128><<<dim3(288, 1), 256, 0, stream>>>(P); }
  halo(C2h, C2l, 96, 96, 2, 128, 100, 100);
  { GemmP P{};  // conv3A: 128ch@96 -> 256ch@48
    P.Ah = w3Ahp; P.Al = w3Alp; P.Bh = C2h; P.Bl = C2l;
    P.C = CORRA; P.F = TA;
    P.M = 256; P.N = B * 48 * 48; P.K = 3200; P.Cip = 128;
    P.Ho = 48; P.Wo = 48; P.HoWo = 2304; P.stride = 2; P.KW = 5;
    P.Hp = 100; P.Wp = 100;
    gemm_conv<128><<<dim3(72, 2), 256, 0, stream>>>(P); }

  // ---- 3. branch B (reuses T1/C2) ----
  { dim3 g(cdiv(192 * 192, 256), 4, B);
    conv_direct_nhwc<7, 16><<<g, 256, 0, stream>>>(
        im2, wB1, nullptr, T1h, T1l, 3, 384, 384, 192, 192, 2, 3,
        64, 196, 196, 2, 0); }
  halo(T1h, T1l, 192, 192, 2, 64, 196, 196);
  { GemmP P{};  // conv2B
    P.Ah = w2Bhp; P.Al = w2Blp; P.Bh = T1h; P.Bl = T1l;
    P.Nh = C2h; P.Nl = C2l;
    P.M = 128; P.N = B * 96 * 96; P.K = 1600; P.Cip = 64;
    P.Ho = 96; P.Wo = 96; P.HoWo = 9216; P.stride = 2; P.KW = 5;
    P.Hp = 196; P.Wp = 196; P.Hp2 = 100; P.Wp2 = 100; P.pad2 = 2;
    gemm_conv<128><<<dim3(288, 1), 256, 0, stream>>>(P); }
  halo(C2h, C2l, 96, 96, 2, 128, 100, 100);
  { GemmP P{};  // conv3B -> TB only
    P.Ah = w3Bhp; P.Al = w3Blp; P.Bh = C2h; P.Bl = C2l;
    P.F = TB;
    P.M = 256; P.N = B * 48 * 48; P.K = 3200; P.Cip = 128;
    P.Ho = 48; P.Wo = 48; P.HoWo = 2304; P.stride = 2; P.KW = 5;
    P.Hp = 100; P.Wp = 100;
    gemm_conv<128><<<dim3(72, 2), 256, 0, stream>>>(P); }

  // ---- 4. late weight packs (T1/C2 now dead) ----
  pack(w4_1, w41hp, w41lp, 512, 512, 512, 3, 3);
  pack(w5, w5hp, w5lp, 512, 512, 512, 3, 3);
  pack(w5_1, w51hp, w51lp, 512, 512, 512, 3, 3);
  pack(w6, w6hp, w6lp, 1024, 512, 512, 3, 3);

  // ---- 5. redir + correlation -> X ----
  { dim3 g(cdiv(48 * 48, 256), 4, B);
    conv_direct_nhwc<1, 8><<<g, 256, 0, stream>>>(
        CORRA, w_redir, b_redir, Xh, Xl, 256, 48, 48, 48, 48, 1, 0,
        480, 50, 50, 1, 441); }
  { dim3 g(144, B);
    corr_kernel<<<g, 256, 0, stream>>>(TA, TB, Xh, Xl); }
  halo(Xh, Xl, 48, 48, 1, 480, 50, 50);

  // ---- 6. encoder GEMMs ----
  { GemmP P{};  // w3_1: 473(480)->256 @48
    P.Ah = w31hp; P.Al = w31lp; P.Bh = Xh; P.Bl = Xl;
    P.C = X2f; P.Nh = X2h; P.Nl = X2l;
    P.M = 256; P.N = 9216; P.K = 4320; P.Cip = 480;
    P.Ho = 48; P.Wo = 48; P.HoWo = 2304; P.stride = 1; P.KW = 3;
    P.Hp = 50; P.Wp = 50; P.Hp2 = 50; P.Wp2 = 50; P.pad2 = 1;
    gemm_conv<128><<<dim3(72, 2), 256, 0, stream>>>(P); }
  halo(X2h, X2l, 48, 48, 1, 256, 50, 50);
  { GemmP P{};  // w4: 256->512, s2, 48->24  (tile 64: 288 blocks)
    P.Ah = w4hp; P.Al = w4lp; P.Bh = X2h; P.Bl = X2l;
    P.Nh = T3h; P.Nl = T3l;
    P.M = 512; P.N = 2304; P.K = 2304; P.Cip = 256;
    P.Ho = 24; P.Wo = 24; P.HoWo = 576; P.stride = 2; P.KW = 3;
    P.Hp = 50; P.Wp = 50; P.Hp2 = 26; P.Wp2 = 26; P.pad2 = 1;
    gemm_conv<64><<<dim3(36, 8), 256, 0, stream>>>(P); }
  halo(T3h, T3l, 24, 24, 1, 512, 26, 26);
  { GemmP P{};  // w4_1: 512->512 @24  (tile 64: 288 blocks)
    P.Ah = w41hp; P.Al = w41lp; P.Bh = T3h; P.Bl = T3l;
    P.C = X3f; P.Nh = X3h; P.Nl = X3l;
    P.M = 512; P.N = 2304; P.K = 4608; P.Cip = 512;
    P.Ho = 24; P.Wo = 24; P.HoWo = 576; P.stride = 1; P.KW = 3;
    P.Hp = 26; P.Wp = 26; P.Hp2 = 26; P.Wp2 = 26; P.pad2 = 1;
    gemm_conv<64><<<dim3(36, 8), 256, 0, stream>>>(P); }
  halo(X3h, X3l, 24, 24, 1, 512, 26, 26);
  { GemmP P{};  // w5: 512->512, s2, 24->12  (tile 64: 72 blocks)
    P.Ah = w5hp; P.Al = w5lp; P.Bh = X3h; P.Bl = X3l;
    P.Nh = T4h; P.Nl = T4l;
    P.M = 512; P.N = 576; P.K = 4608; P.Cip = 512;
    P.Ho = 12; P.Wo = 12; P.HoWo = 144; P.stride = 2; P.KW = 3;
    P.Hp = 26; P.Wp = 26; P.Hp2 = 14; P.Wp2 = 14; P.pad2 = 1;
    gemm_conv<64><<<dim3(9, 8), 256, 0, stream>>>(P); }
  halo(T4h, T4l, 12, 12, 1, 512, 14, 14);
  { GemmP P{};  // w5_1: 512->512 @12  (tile 64: 72 blocks)
    P.Ah = w51hp; P.Al = w51lp; P.Bh = T4h; P.Bl = T4l;
    P.C = X4f; P.Nh = X4h; P.Nl = X4l;
    P.M = 512; P.N = 576; P.K = 4608; P.Cip = 512;
    P.Ho = 12; P.Wo = 12; P.HoWo = 144; P.stride = 1; P.KW = 3;
    P.Hp = 14; P.Wp = 14; P.Hp2 = 14; P.Wp2 = 14; P.pad2 = 1;
    gemm_conv<64><<<dim3(9, 8), 256, 0, stream>>>(P); }
  halo(X4h, X4l, 12, 12, 1, 512, 14, 14);
  { GemmP P{};  // w6: 512->1024, s2, 12->6  (tile 64: 48 blocks)
    P.Ah = w6hp; P.Al = w6lp; P.Bh = X4h; P.Bl = X4l;
    P.C = X5f;
    P.M = 1024; P.N = 144; P.K = 4608; P.Cip = 512;
    P.Ho = 6; P.Wo = 6; P.HoWo = 36; P.stride = 2; P.KW = 3;
    P.Hp = 14; P.Wp = 14;
    gemm_conv<64><<<dim3(3, 16), 256, 0, stream>>>(P); }

  // ---- 7. decoder (fp32; buffers overlay dead R2) ----
  { dim3 g(cdiv(512 * 36, 256), B);  upconv_kernel<<<g, 256, 0, stream>>>(X5f, wd5, Y5, 1024, 512, 6, 6, 1024, 0); }
  { dim3 g(cdiv(512 * 144, 256), B); copy_ch<<<g, 256, 0, stream>>>(X4f, Y5, 512, 144, 1024, 512); }
  hipMemsetAsync(F5, 0, 1152 * sizeof(float), stream);
  { dim3 g(cdiv(144, 64), cdiv(1024, 64), B); conv5_splitk<<<g, 64, 0, stream>>>(Y5, wf5, F5, 1024, 12, 12, 64); }

  { dim3 g(cdiv(256 * 144, 256), B); upconv_kernel<<<g, 256, 0, stream>>>(Y5, wd4, Y4, 1024, 256, 12, 12, 770, 0); }
  { dim3 g(cdiv(512 * 576, 256), B); copy_ch<<<g, 256, 0, stream>>>(X3f, Y4, 512, 576, 770, 256); }
  { dim3 g(cdiv(2 * 576, 256), B);   upsample_bilinear<<<g, 256, 0, stream>>>(F5, Y4, 2, 12, 12, 24, 24, 770, 768); }
  hipMemsetAsync(F4, 0, 4608 * sizeof(float), stream);
  { dim3 g(cdiv(576, 64), cdiv(770, 64), B); conv5_splitk<<<g, 64, 0, stream>>>(Y4, wf4, F4, 770, 24, 24, 64); }

  { dim3 g(cdiv(128 * 576, 256), B);  upconv_kernel<<<g, 256, 0, stream>>>(Y4, wd3, Y3, 770, 128, 24, 24, 386, 0); }
  { dim3 g(cdiv(256 * 2304, 256), B); copy_ch<<<g, 256, 0, stream>>>(X2f, Y3, 256, 2304, 386, 128); }
  { dim3 g(cdiv(2 * 2304, 256), B);   upsample_bilinear<<<g, 256, 0, stream>>>(F4, Y3, 2, 24, 24, 48, 48, 386, 384); }
  hipMemsetAsync(F3, 0, 18432 * sizeof(float), stream);
  { dim3 g(cdiv(2304, 256), cdiv(386, 64), B); conv5_splitk<<<g, 256, 0, stream>>>(Y3, wf3, F3, 386, 48, 48, 64); }

  { dim3 g(cdiv(64 * 2304, 256), B);  upconv_kernel<<<g, 256, 0, stream>>>(Y3, wd2, Y2, 386, 64, 48, 48, 194, 0); }
  { dim3 g(cdiv(128 * 9216, 256), B); copy_ch<<<g, 256, 0, stream>>>(A, Y2, 128, 9216, 194, 64); }
  { dim3 g(cdiv(2 * 9216, 256), B);   upsample_bilinear<<<g, 256, 0, stream>>>(F3, Y2, 2, 48, 48, 96, 96, 194, 192); }
  hipMemsetAsync(PRED, 0, 73728 * sizeof(float), stream);
  { dim3 g(cdiv(9216, 256), cdiv(194, 64), B); conv5_splitk<<<g, 256, 0, stream>>>(Y2, wpred, PRED, 194, 96, 96, 64); }

  { dim3 g(cdiv(2 * 384 * 384, 256), B);
    upsample_bilinear<<<g, 256, 0, stream>>>(PRED, (float*)d_out, 2, 96, 96, 384, 384, 2, 0); }
}